// Round 6
// baseline (279.131 us; speedup 1.0000x reference)
//
#include <hip/hip_runtime.h>

// B=4, T=2048, C=1024, H=16, D=64. fp32 in/out, bf16 internal compute.

typedef unsigned short u16;
typedef unsigned int u32;
typedef __attribute__((ext_vector_type(8))) unsigned short u16x8;
typedef __attribute__((ext_vector_type(4))) unsigned short u16x4;
typedef __attribute__((ext_vector_type(8))) short short8;
typedef __attribute__((ext_vector_type(4))) float f32x4;

__device__ inline u16 f2bf(float f) {
  unsigned u = __float_as_uint(f);
  u = (u + 0x7FFF + ((u >> 16) & 1)) >> 16;  // RNE
  return (u16)u;
}

__device__ inline f32x4 mfma16(short8 a, short8 b, f32x4 c) {
  return __builtin_amdgcn_mfma_f32_16x16x32_bf16(a, b, c, 0, 0, 0);
}

__device__ inline void gld16(const void* g, void* l) {
  __builtin_amdgcn_global_load_lds(
      (const __attribute__((address_space(1))) void*)g,
      (__attribute__((address_space(3))) void*)l, 16, 0, 0);
}

// ---------------- fp32 -> bf16 elementwise convert ----------------
__global__ __launch_bounds__(256) void k_cvt(const float* __restrict__ in,
                                             u16* __restrict__ out) {
  int i = (blockIdx.x * 256 + threadIdx.x) * 4;
  float4 v = *(const float4*)(in + i);
  u16x4 o = {f2bf(v.x), f2bf(v.y), f2bf(v.z), f2bf(v.w)};
  *(u16x4*)(out + i) = o;
}

// ------------- fp32 [R][Cc] -> bf16 transpose [Cc][R] -------------
__global__ __launch_bounds__(256) void k_tw(const float* __restrict__ in,
                                            u16* __restrict__ outT, int R, int Cc) {
  __shared__ u16 t[64][65];
  int c0 = blockIdx.x * 64, r0 = blockIdx.y * 64;
  int a = threadIdx.x & 63, w = threadIdx.x >> 6;
#pragma unroll
  for (int j = 0; j < 16; ++j) {
    int r = w + j * 4;
    t[r][a] = f2bf(in[(size_t)(r0 + r) * Cc + c0 + a]);
  }
  __syncthreads();
#pragma unroll
  for (int j = 0; j < 16; ++j) {
    int c = w + j * 4;
    outT[(size_t)(c0 + c) * R + r0 + a] = t[a][c];
  }
}

// ------- V slice of qkv -> Vt[b][h][d][t]  (bf16 transpose) -------
__global__ __launch_bounds__(256) void k_tv(const u16* __restrict__ qkv,
                                            u16* __restrict__ vt) {
  __shared__ u16 t[64][65];
  int t0 = blockIdx.x * 64, h = blockIdx.y, b = blockIdx.z;
  int a = threadIdx.x & 63, w = threadIdx.x >> 6;
#pragma unroll
  for (int j = 0; j < 16; ++j) {
    int tr = w + j * 4;
    t[tr][a] = qkv[(size_t)(b * 2048 + t0 + tr) * 3072 + 2048 + h * 64 + a];
  }
  __syncthreads();
#pragma unroll
  for (int j = 0; j < 16; ++j) {
    int d = w + j * 4;
    vt[((size_t)((b * 16 + h) * 64 + d)) * 2048 + t0 + a] = t[a][d];
  }
}

// ---- bf16 GEMM: A[M][K] x Bt[N][K] + bias -> bf16 or fp32 out ----
// Block tile 256x128, 4 waves, wave tile 128x64 (8x4 MFMA 16x16x32):
// 22 FLOP per LDS byte (vs 16 at 64x64 wave tile) — LDS-pipe relief.
// XOR bank swizzle: chunk q of row R stored at slot q^((R>>1)&3) (staged by
// permuting the GLOBAL source chunk per lane; global_load_lds LDS dest stays
// lane-contiguous). Frag reads at slot quad^((l16>>1)&3) → start banks spread
// across 8 groups (2-way aliasing = free) instead of 2 (8-way conflict).
// QSCALE: multiply cols<1024 (Q slice of qkv) by 1/sqrt(64)*log2(e).
template <int OUTBF, int QSCALE>
__global__ __launch_bounds__(256, 2) void gemm_bt(const u16* __restrict__ A,
                                                  const u16* __restrict__ Bt,
                                                  const float* __restrict__ bias,
                                                  u16* __restrict__ outb,
                                                  float* __restrict__ outf,
                                                  int M, int N, int K) {
  __shared__ u16 As[256 * 32];
  __shared__ u16 Bs[128 * 32];
  const int m0 = blockIdx.x * 256, n0 = blockIdx.y * 128;
  const int tid = threadIdx.x, wave = tid >> 6, lane = tid & 63;
  const int quad = lane >> 4, l16 = lane & 15;
  const int wm = (wave >> 1) * 128, wn = (wave & 1) * 64;
  const int sw = (l16 >> 1) & 3;  // frag-read swizzle
  // staging: lane covers row rbase+j*16+(lane>>2), global chunk permuted
  const int gch = (lane & 3) ^ ((lane >> 3) & 3);
  const int lrow = lane >> 2;
  const u16* pa0 = A + (size_t)(m0 + wave * 64 + 0 + lrow) * K + gch * 8;
  const u16* pa1 = A + (size_t)(m0 + wave * 64 + 16 + lrow) * K + gch * 8;
  const u16* pa2 = A + (size_t)(m0 + wave * 64 + 32 + lrow) * K + gch * 8;
  const u16* pa3 = A + (size_t)(m0 + wave * 64 + 48 + lrow) * K + gch * 8;
  const u16* pb0 = Bt + (size_t)(n0 + wave * 32 + 0 + lrow) * K + gch * 8;
  const u16* pb1 = Bt + (size_t)(n0 + wave * 32 + 16 + lrow) * K + gch * 8;
  u16* la0 = As + (wave * 256 + 0) * 8;    // chunk base *8 elems
  u16* la1 = As + (wave * 256 + 64) * 8;
  u16* la2 = As + (wave * 256 + 128) * 8;
  u16* la3 = As + (wave * 256 + 192) * 8;
  u16* lb0 = Bs + (wave * 128 + 0) * 8;
  u16* lb1 = Bs + (wave * 128 + 64) * 8;
  f32x4 acc[8][4] = {};
  for (int kt = 0; kt < K; kt += 32) {
    __syncthreads();
    gld16(pa0 + kt, la0);
    gld16(pa1 + kt, la1);
    gld16(pa2 + kt, la2);
    gld16(pa3 + kt, la3);
    gld16(pb0 + kt, lb0);
    gld16(pb1 + kt, lb1);
    __syncthreads();
    short8 af[8], bf[4];
#pragma unroll
    for (int mt = 0; mt < 8; ++mt)
      af[mt] = *(const short8*)(As + (wm + mt * 16 + l16) * 32 + (quad ^ sw) * 8);
#pragma unroll
    for (int nt = 0; nt < 4; ++nt)
      bf[nt] = *(const short8*)(Bs + (wn + nt * 16 + l16) * 32 + (quad ^ sw) * 8);
#pragma unroll
    for (int mt = 0; mt < 8; ++mt)
#pragma unroll
      for (int nt = 0; nt < 4; ++nt)
        acc[mt][nt] = mfma16(af[mt], bf[nt], acc[mt][nt]);
  }
#pragma unroll
  for (int nt = 0; nt < 4; ++nt) {
    int col = n0 + wn + nt * 16 + l16;
    float bv = bias[col];
#pragma unroll
    for (int mt = 0; mt < 8; ++mt) {
      int rowb = m0 + wm + mt * 16 + quad * 4;
#pragma unroll
      for (int r = 0; r < 4; ++r) {
        float v = acc[mt][nt][r] + bv;
        if (QSCALE && col < 1024) v *= 0.18033688f;  // 0.125 * log2(e)
        if (OUTBF)
          outb[(size_t)(rowb + r) * N + col] = f2bf(v);
        else
          outf[(size_t)(rowb + r) * N + col] = v;
      }
    }
  }
}

// ----------------- fused causal flash attention -------------------
// grid (8, H, B): block p handles 128-row q-tiles {p, 15-p} → uniform 34
// k-tiles/block. Each wave owns TWO 16-row q-groups so every K/V LDS
// fragment read feeds 2 MFMAs. Fixed-reference softmax (Q pre-scaled by
// 0.125*log2e in gemm1; offset cancels in O/l — exact). l on the MFMA pipe
// (P·ones), C/D rows match o[]. Group-0 diagonal at nkt-2; skips nkt-1.
// LDS: P aliases the 128-row Q region (wave-private rows, in-order DS).
#define ATP 72  // LDS row stride (elems): 144B = 9x16B, conflict-light
__global__ __launch_bounds__(256) void attn(const u16* __restrict__ qkv,
                                            const u16* __restrict__ vt,
                                            u16* __restrict__ y) {
  __shared__ u16 shm[256 * ATP];  // 36.9 KB
  u16* Qs = shm;                  // 128 rows; aliased as P after frag reads
  u16* Ks = shm + 128 * ATP;      // 64 rows
  u16* Vs = shm + 192 * ATP;      // 64 rows, V^T: [d][t]
  const int p = blockIdx.x, h = blockIdx.y, b = blockIdx.z;
  const int tid = threadIdx.x, wave = tid >> 6, lane = tid & 63;
  const int quad = lane >> 4, l16 = lane & 15;
  const u16* Qg = qkv + (size_t)b * 2048 * 3072 + h * 64;
  const u16* Kg = Qg + 1024;
  const u16* Vtg = vt + (size_t)(b * 16 + h) * 64 * 2048;
  const int srow0 = tid >> 3, scol0 = (tid & 7) * 8;  // srow0 in [0,32)
  u16* Pw0 = Qs + (wave * 16) * ATP;        // group-0 P (wave-private rows)
  u16* Pw1 = Qs + (64 + wave * 16) * ATP;   // group-1 P
  short8 ones_f;
#pragma unroll
  for (int j = 0; j < 8; ++j) ones_f[j] = 0x3F80;  // bf16 1.0

  for (int half = 0; half < 2; ++half) {
    const int qb = half ? (15 - p) : p;
    const int q0 = qb * 128;
    const int nkt = 2 * qb + 2;
    const u16* kp0 = Kg + (size_t)srow0 * 3072 + scol0;
    const u16* kp1 = kp0 + 32 * 3072;
    const u16* vp0 = Vtg + (size_t)srow0 * 2048 + scol0;
    const u16* vp1 = vp0 + 32 * 2048;
    // ---- load Q 128x64 + K/V tile 0 into regs ----
    u16x8 qr0 = *(const u16x8*)(Qg + (size_t)(q0 + srow0) * 3072 + scol0);
    u16x8 qr1 = *(const u16x8*)(Qg + (size_t)(q0 + srow0 + 32) * 3072 + scol0);
    u16x8 qr2 = *(const u16x8*)(Qg + (size_t)(q0 + srow0 + 64) * 3072 + scol0);
    u16x8 qr3 = *(const u16x8*)(Qg + (size_t)(q0 + srow0 + 96) * 3072 + scol0);
    u16x8 kreg0 = *(const u16x8*)kp0, kreg1 = *(const u16x8*)kp1;
    u16x8 vreg0 = *(const u16x8*)vp0, vreg1 = *(const u16x8*)vp1;
    __syncthreads();  // previous q-tile's LDS reads (incl. P) complete
    *(u16x8*)&Qs[(size_t)srow0 * ATP + scol0] = qr0;
    *(u16x8*)&Qs[(size_t)(srow0 + 32) * ATP + scol0] = qr1;
    *(u16x8*)&Qs[(size_t)(srow0 + 64) * ATP + scol0] = qr2;
    *(u16x8*)&Qs[(size_t)(srow0 + 96) * ATP + scol0] = qr3;
    *(u16x8*)&Ks[(size_t)srow0 * ATP + scol0] = kreg0;
    *(u16x8*)&Ks[(size_t)(srow0 + 32) * ATP + scol0] = kreg1;
    *(u16x8*)&Vs[(size_t)srow0 * ATP + scol0] = vreg0;
    *(u16x8*)&Vs[(size_t)(srow0 + 32) * ATP + scol0] = vreg1;
    __syncthreads();
    // Q fragments for both groups (wave reads only its own P-alias rows)
    short8 qf0a = *(const short8*)&Qs[(wave * 16 + l16) * ATP + quad * 8];
    short8 qf1a = *(const short8*)&Qs[(wave * 16 + l16) * ATP + 32 + quad * 8];
    short8 qf0b = *(const short8*)&Qs[(64 + wave * 16 + l16) * ATP + quad * 8];
    short8 qf1b = *(const short8*)&Qs[(64 + wave * 16 + l16) * ATP + 32 + quad * 8];

    f32x4 lacc0 = {}, lacc1 = {};
    f32x4 o0[4] = {}, o1[4] = {};

    // g0mode: 0=full, 1=diag-mask, 2=skip. g1mask: diag-mask group 1.
    auto tile = [&](int kt, int g0mode, bool g1mask) {
      if (kt > 0) {
        __syncthreads();  // all waves done reading tile kt-1
        *(u16x8*)&Ks[(size_t)srow0 * ATP + scol0] = kreg0;
        *(u16x8*)&Ks[(size_t)(srow0 + 32) * ATP + scol0] = kreg1;
        *(u16x8*)&Vs[(size_t)srow0 * ATP + scol0] = vreg0;
        *(u16x8*)&Vs[(size_t)(srow0 + 32) * ATP + scol0] = vreg1;
        __syncthreads();
      }
      if (kt + 1 < nkt) {  // prefetch next K/V tile
        kreg0 = *(const u16x8*)(kp0 += 64 * 3072);
        kreg1 = *(const u16x8*)(kp1 += 64 * 3072);
        vreg0 = *(const u16x8*)(vp0 += 64);
        vreg1 = *(const u16x8*)(vp1 += 64);
      }

      // S^T = K . Q^T for both groups; kf fragments shared
      f32x4 s0[4] = {}, s1[4] = {};
#pragma unroll
      for (int mt = 0; mt < 4; ++mt) {
        short8 kf0 = *(const short8*)&Ks[(mt * 16 + l16) * ATP + quad * 8];
        short8 kf1 = *(const short8*)&Ks[(mt * 16 + l16) * ATP + 32 + quad * 8];
        if (g0mode < 2) {
          s0[mt] = mfma16(kf0, qf0a, s0[mt]);
          s0[mt] = mfma16(kf1, qf1a, s0[mt]);
        }
        s1[mt] = mfma16(kf0, qf0b, s1[mt]);
        s1[mt] = mfma16(kf1, qf1b, s1[mt]);
      }

      // softmax + P pack, group 0
      if (g0mode < 2) {
        const int qrow = q0 + wave * 16 + l16;
#pragma unroll
        for (int mt = 0; mt < 4; ++mt) {
          float pe[4];
#pragma unroll
          for (int r = 0; r < 4; ++r) {
            float pv = __builtin_amdgcn_exp2f(s0[mt][r]);
            if (g0mode == 1) {
              int kcol = kt * 64 + mt * 16 + quad * 4 + r;
              if (kcol > qrow) pv = 0.f;
            }
            pe[r] = pv;
          }
          u32 lo = __builtin_amdgcn_perm(__float_as_uint(pe[1]),
                                         __float_as_uint(pe[0]), 0x07060302u);
          u32 hi = __builtin_amdgcn_perm(__float_as_uint(pe[3]),
                                         __float_as_uint(pe[2]), 0x07060302u);
          uint2 pk = {lo, hi};
          *(uint2*)&Pw0[l16 * ATP + mt * 16 + quad * 4] = pk;
        }
      }
      // softmax + P pack, group 1
      {
        const int qrow = q0 + 64 + wave * 16 + l16;
#pragma unroll
        for (int mt = 0; mt < 4; ++mt) {
          float pe[4];
#pragma unroll
          for (int r = 0; r < 4; ++r) {
            float pv = __builtin_amdgcn_exp2f(s1[mt][r]);
            if (g1mask) {
              int kcol = kt * 64 + mt * 16 + quad * 4 + r;
              if (kcol > qrow) pv = 0.f;
            }
            pe[r] = pv;
          }
          u32 lo = __builtin_amdgcn_perm(__float_as_uint(pe[1]),
                                         __float_as_uint(pe[0]), 0x07060302u);
          u32 hi = __builtin_amdgcn_perm(__float_as_uint(pe[3]),
                                         __float_as_uint(pe[2]), 0x07060302u);
          uint2 pk = {lo, hi};
          *(uint2*)&Pw1[l16 * ATP + mt * 16 + quad * 4] = pk;
        }
      }

      // O += P.V ; l += P.1 — vf fragments shared between groups
#pragma unroll
      for (int ks = 0; ks < 2; ++ks) {
        short8 pf0, pf1;
        if (g0mode < 2) {
          pf0 = *(const short8*)&Pw0[l16 * ATP + ks * 32 + quad * 8];
          lacc0 = mfma16(pf0, ones_f, lacc0);
        }
        pf1 = *(const short8*)&Pw1[l16 * ATP + ks * 32 + quad * 8];
        lacc1 = mfma16(pf1, ones_f, lacc1);
#pragma unroll
        for (int dt = 0; dt < 4; ++dt) {
          short8 vf = *(const short8*)&Vs[(dt * 16 + l16) * ATP + ks * 32 + quad * 8];
          if (g0mode < 2) o0[dt] = mfma16(pf0, vf, o0[dt]);
          o1[dt] = mfma16(pf1, vf, o1[dt]);
        }
      }
    };

    for (int kt = 0; kt < nkt - 2; ++kt) tile(kt, 0, false);
    tile(nkt - 2, 1, false);  // group-0 diagonal; group 1 still full
    tile(nkt - 1, 2, true);   // group-1 diagonal; group 0 fully masked: skip

    // epilogue: lacc reg r = l for row quad*4+r — same rows as o[dt][r]
    size_t rb0 = (size_t)b * 2048 + q0 + wave * 16 + quad * 4;
#pragma unroll
    for (int r = 0; r < 4; ++r) {
      float inv = 1.f / lacc0[r];
#pragma unroll
      for (int dt = 0; dt < 4; ++dt)
        y[(rb0 + r) * 1024 + h * 64 + dt * 16 + l16] = f2bf(o0[dt][r] * inv);
    }
    size_t rb1 = rb0 + 64;
#pragma unroll
    for (int r = 0; r < 4; ++r) {
      float inv = 1.f / lacc1[r];
#pragma unroll
      for (int dt = 0; dt < 4; ++dt)
        y[(rb1 + r) * 1024 + h * 64 + dt * 16 + l16] = f2bf(o1[dt][r] * inv);
    }
  }
}

extern "C" void kernel_launch(void* const* d_in, const int* in_sizes, int n_in,
                              void* d_out, int out_size, void* d_ws, size_t ws_size,
                              hipStream_t stream) {
  const float* x = (const float*)d_in[0];
  const float* W_attn = (const float*)d_in[1];
  const float* b_attn = (const float*)d_in[2];
  const float* W_proj = (const float*)d_in[3];
  const float* b_proj = (const float*)d_in[4];
  float* out = (float*)d_out;
  char* ws = (char*)d_ws;
  u16* xb  = (u16*)(ws);               // x as bf16 [8192][1024]
  u16* wta = (u16*)(ws + 16777216);    // W_attn^T bf16 [3072][1024]
  u16* wtp = (u16*)(ws + 23068672);    // W_proj^T bf16 [1024][1024]
  u16* qkv = (u16*)(ws + 25165824);    // qkv bf16 [8192][3072] (Q pre-scaled)
  u16* vt  = (u16*)(ws + 75497472);    // V^T bf16 [b][h][64][2048]
  u16* y   = (u16*)(ws + 92274688);    // attn out bf16 [8192][1024]

  k_cvt<<<dim3(8192), 256, 0, stream>>>(x, xb);
  k_tw<<<dim3(48, 16), 256, 0, stream>>>(W_attn, wta, 1024, 3072);
  k_tw<<<dim3(16, 16), 256, 0, stream>>>(W_proj, wtp, 1024, 1024);
  gemm_bt<1, 1><<<dim3(32, 24), 256, 0, stream>>>(xb, wta, b_attn, qkv, nullptr, 8192, 3072, 1024);
  k_tv<<<dim3(32, 16, 4), 256, 0, stream>>>(qkv, vt);
  attn<<<dim3(8, 16, 4), 256, 0, stream>>>(qkv, vt, y);
  gemm_bt<0, 0><<<dim3(32, 8), 256, 0, stream>>>(y, wtp, b_proj, nullptr, out, 8192, 1024, 1024);
}

// Round 7
// 254.218 us; speedup vs baseline: 1.0980x; 1.0980x over previous
//
#include <hip/hip_runtime.h>

// B=4, T=2048, C=1024, H=16, D=64. fp32 in/out, bf16 internal compute.

typedef unsigned short u16;
typedef unsigned int u32;
typedef __attribute__((ext_vector_type(8))) unsigned short u16x8;
typedef __attribute__((ext_vector_type(4))) unsigned short u16x4;
typedef __attribute__((ext_vector_type(8))) short short8;
typedef __attribute__((ext_vector_type(4))) float f32x4;

__device__ inline u16 f2bf(float f) {
  unsigned u = __float_as_uint(f);
  u = (u + 0x7FFF + ((u >> 16) & 1)) >> 16;  // RNE
  return (u16)u;
}

__device__ inline f32x4 mfma16(short8 a, short8 b, f32x4 c) {
  return __builtin_amdgcn_mfma_f32_16x16x32_bf16(a, b, c, 0, 0, 0);
}

__device__ inline void gld16(const void* g, void* l) {
  __builtin_amdgcn_global_load_lds(
      (const __attribute__((address_space(1))) void*)g,
      (__attribute__((address_space(3))) void*)l, 16, 0, 0);
}

// ---------------- fp32 -> bf16 elementwise convert ----------------
__global__ __launch_bounds__(256) void k_cvt(const float* __restrict__ in,
                                             u16* __restrict__ out) {
  int i = (blockIdx.x * 256 + threadIdx.x) * 4;
  float4 v = *(const float4*)(in + i);
  u16x4 o = {f2bf(v.x), f2bf(v.y), f2bf(v.z), f2bf(v.w)};
  *(u16x4*)(out + i) = o;
}

// ------------- fp32 [R][Cc] -> bf16 transpose [Cc][R] -------------
__global__ __launch_bounds__(256) void k_tw(const float* __restrict__ in,
                                            u16* __restrict__ outT, int R, int Cc) {
  __shared__ u16 t[64][65];
  int c0 = blockIdx.x * 64, r0 = blockIdx.y * 64;
  int a = threadIdx.x & 63, w = threadIdx.x >> 6;
#pragma unroll
  for (int j = 0; j < 16; ++j) {
    int r = w + j * 4;
    t[r][a] = f2bf(in[(size_t)(r0 + r) * Cc + c0 + a]);
  }
  __syncthreads();
#pragma unroll
  for (int j = 0; j < 16; ++j) {
    int c = w + j * 4;
    outT[(size_t)(c0 + c) * R + r0 + a] = t[a][c];
  }
}

// ------- V slice of qkv -> Vt[b][h][d][t]  (bf16 transpose) -------
__global__ __launch_bounds__(256) void k_tv(const u16* __restrict__ qkv,
                                            u16* __restrict__ vt) {
  __shared__ u16 t[64][65];
  int t0 = blockIdx.x * 64, h = blockIdx.y, b = blockIdx.z;
  int a = threadIdx.x & 63, w = threadIdx.x >> 6;
#pragma unroll
  for (int j = 0; j < 16; ++j) {
    int tr = w + j * 4;
    t[tr][a] = qkv[(size_t)(b * 2048 + t0 + tr) * 3072 + 2048 + h * 64 + a];
  }
  __syncthreads();
#pragma unroll
  for (int j = 0; j < 16; ++j) {
    int d = w + j * 4;
    vt[((size_t)((b * 16 + h) * 64 + d)) * 2048 + t0 + a] = t[a][d];
  }
}

// ---- bf16 GEMM: A[M][K] x Bt[N][K] + bias -> bf16 or fp32 out ----
// 128x128 block tile (4-5 blocks/CU residency — hides barrier drain),
// BK=64 (half the barriers of BK=32; same LDS bytes per unit K).
// Row stride 64 elems = 128B → every row starts at bank 0; chunk c of row r
// stored at slot c^(r&7) (global source chunk permuted per lane — the
// global_load_lds LDS dest stays lane-contiguous). Fragment reads then give
// each consecutive-8-lane service group 8 distinct start banks → 0 conflicts
// (rule derived from r5[8-way,6.3e6]/r6[distinct,0] measurements).
// QSCALE: multiply cols<1024 (Q slice of qkv) by 1/sqrt(64)*log2(e).
template <int OUTBF, int QSCALE>
__global__ __launch_bounds__(256) void gemm_bt(const u16* __restrict__ A,
                                               const u16* __restrict__ Bt,
                                               const float* __restrict__ bias,
                                               u16* __restrict__ outb,
                                               float* __restrict__ outf,
                                               int M, int N, int K) {
  __shared__ u16 As[128 * 64];
  __shared__ u16 Bs[128 * 64];
  const int m0 = blockIdx.x * 128, n0 = blockIdx.y * 128;
  const int tid = threadIdx.x, wave = tid >> 6, lane = tid & 63;
  const int quad = lane >> 4, l16 = lane & 15;
  const int wm = (wave & 1) * 64, wn = (wave >> 1) * 64;
  // staging: wave w, call j covers rows w*32+j*8 .. +7 (8 rows x 64 cols)
  const int lrow = lane >> 3;                 // 0..7 within the 8-row slab
  const int gch = (lane & 7) ^ lrow;          // permuted global chunk
  const u16* sA[4];
  const u16* sB[4];
  u16* dA[4];
  u16* dB[4];
#pragma unroll
  for (int j = 0; j < 4; ++j) {
    int r = wave * 32 + j * 8;
    sA[j] = A + (size_t)(m0 + r + lrow) * K + gch * 8;
    sB[j] = Bt + (size_t)(n0 + r + lrow) * K + gch * 8;
    dA[j] = As + r * 64;
    dB[j] = Bs + r * 64;
  }
  f32x4 acc[4][4] = {};
  for (int kt = 0; kt < K; kt += 64) {
    __syncthreads();
#pragma unroll
    for (int j = 0; j < 4; ++j) {
      gld16(sA[j] + kt, dA[j]);
      gld16(sB[j] + kt, dB[j]);
    }
    __syncthreads();
#pragma unroll
    for (int ks = 0; ks < 2; ++ks) {
      const int sl = l16 & 7;
      short8 af[4], bf[4];
#pragma unroll
      for (int mt = 0; mt < 4; ++mt)
        af[mt] = *(const short8*)(As + (wm + mt * 16 + l16) * 64 +
                                  (((ks * 4 + quad) ^ sl)) * 8);
#pragma unroll
      for (int nt = 0; nt < 4; ++nt)
        bf[nt] = *(const short8*)(Bs + (wn + nt * 16 + l16) * 64 +
                                  (((ks * 4 + quad) ^ sl)) * 8);
#pragma unroll
      for (int mt = 0; mt < 4; ++mt)
#pragma unroll
        for (int nt = 0; nt < 4; ++nt)
          acc[mt][nt] = mfma16(af[mt], bf[nt], acc[mt][nt]);
    }
  }
#pragma unroll
  for (int nt = 0; nt < 4; ++nt) {
    int col = n0 + wn + nt * 16 + l16;
    float bv = bias[col];
#pragma unroll
    for (int mt = 0; mt < 4; ++mt) {
      int rowb = m0 + wm + mt * 16 + quad * 4;
#pragma unroll
      for (int r = 0; r < 4; ++r) {
        float v = acc[mt][nt][r] + bv;
        if (QSCALE && col < 1024) v *= 0.18033688f;  // 0.125 * log2(e)
        if (OUTBF)
          outb[(size_t)(rowb + r) * N + col] = f2bf(v);
        else
          outf[(size_t)(rowb + r) * N + col] = v;
      }
    }
  }
}

// ----------------- fused causal flash attention -------------------
// grid (8, H, B): block p handles 128-row q-tiles {p, 15-p} → uniform 34
// k-tiles/block. Each wave owns TWO 16-row q-groups so every K/V LDS
// fragment read feeds 2 MFMAs. Fixed-reference softmax (Q pre-scaled by
// 0.125*log2e in gemm1; offset cancels in O/l — exact). l on the MFMA pipe
// (P·ones), C/D rows match o[]. Group-0 diagonal at nkt-2; skips nkt-1.
// LDS: P aliases the 128-row Q region (wave-private rows, in-order DS).
#define ATP 72  // LDS row stride (elems): 144B = 9x16B, conflict-light
__global__ __launch_bounds__(256) void attn(const u16* __restrict__ qkv,
                                            const u16* __restrict__ vt,
                                            u16* __restrict__ y) {
  __shared__ u16 shm[256 * ATP];  // 36.9 KB
  u16* Qs = shm;                  // 128 rows; aliased as P after frag reads
  u16* Ks = shm + 128 * ATP;      // 64 rows
  u16* Vs = shm + 192 * ATP;      // 64 rows, V^T: [d][t]
  const int p = blockIdx.x, h = blockIdx.y, b = blockIdx.z;
  const int tid = threadIdx.x, wave = tid >> 6, lane = tid & 63;
  const int quad = lane >> 4, l16 = lane & 15;
  const u16* Qg = qkv + (size_t)b * 2048 * 3072 + h * 64;
  const u16* Kg = Qg + 1024;
  const u16* Vtg = vt + (size_t)(b * 16 + h) * 64 * 2048;
  const int srow0 = tid >> 3, scol0 = (tid & 7) * 8;  // srow0 in [0,32)
  u16* Pw0 = Qs + (wave * 16) * ATP;        // group-0 P (wave-private rows)
  u16* Pw1 = Qs + (64 + wave * 16) * ATP;   // group-1 P
  short8 ones_f;
#pragma unroll
  for (int j = 0; j < 8; ++j) ones_f[j] = 0x3F80;  // bf16 1.0

  for (int half = 0; half < 2; ++half) {
    const int qb = half ? (15 - p) : p;
    const int q0 = qb * 128;
    const int nkt = 2 * qb + 2;
    const u16* kp0 = Kg + (size_t)srow0 * 3072 + scol0;
    const u16* kp1 = kp0 + 32 * 3072;
    const u16* vp0 = Vtg + (size_t)srow0 * 2048 + scol0;
    const u16* vp1 = vp0 + 32 * 2048;
    // ---- load Q 128x64 + K/V tile 0 into regs ----
    u16x8 qr0 = *(const u16x8*)(Qg + (size_t)(q0 + srow0) * 3072 + scol0);
    u16x8 qr1 = *(const u16x8*)(Qg + (size_t)(q0 + srow0 + 32) * 3072 + scol0);
    u16x8 qr2 = *(const u16x8*)(Qg + (size_t)(q0 + srow0 + 64) * 3072 + scol0);
    u16x8 qr3 = *(const u16x8*)(Qg + (size_t)(q0 + srow0 + 96) * 3072 + scol0);
    u16x8 kreg0 = *(const u16x8*)kp0, kreg1 = *(const u16x8*)kp1;
    u16x8 vreg0 = *(const u16x8*)vp0, vreg1 = *(const u16x8*)vp1;
    __syncthreads();  // previous q-tile's LDS reads (incl. P) complete
    *(u16x8*)&Qs[(size_t)srow0 * ATP + scol0] = qr0;
    *(u16x8*)&Qs[(size_t)(srow0 + 32) * ATP + scol0] = qr1;
    *(u16x8*)&Qs[(size_t)(srow0 + 64) * ATP + scol0] = qr2;
    *(u16x8*)&Qs[(size_t)(srow0 + 96) * ATP + scol0] = qr3;
    *(u16x8*)&Ks[(size_t)srow0 * ATP + scol0] = kreg0;
    *(u16x8*)&Ks[(size_t)(srow0 + 32) * ATP + scol0] = kreg1;
    *(u16x8*)&Vs[(size_t)srow0 * ATP + scol0] = vreg0;
    *(u16x8*)&Vs[(size_t)(srow0 + 32) * ATP + scol0] = vreg1;
    __syncthreads();
    // Q fragments for both groups (wave reads only its own P-alias rows)
    short8 qf0a = *(const short8*)&Qs[(wave * 16 + l16) * ATP + quad * 8];
    short8 qf1a = *(const short8*)&Qs[(wave * 16 + l16) * ATP + 32 + quad * 8];
    short8 qf0b = *(const short8*)&Qs[(64 + wave * 16 + l16) * ATP + quad * 8];
    short8 qf1b = *(const short8*)&Qs[(64 + wave * 16 + l16) * ATP + 32 + quad * 8];

    f32x4 lacc0 = {}, lacc1 = {};
    f32x4 o0[4] = {}, o1[4] = {};

    // g0mode: 0=full, 1=diag-mask, 2=skip. g1mask: diag-mask group 1.
    auto tile = [&](int kt, int g0mode, bool g1mask) {
      if (kt > 0) {
        __syncthreads();  // all waves done reading tile kt-1
        *(u16x8*)&Ks[(size_t)srow0 * ATP + scol0] = kreg0;
        *(u16x8*)&Ks[(size_t)(srow0 + 32) * ATP + scol0] = kreg1;
        *(u16x8*)&Vs[(size_t)srow0 * ATP + scol0] = vreg0;
        *(u16x8*)&Vs[(size_t)(srow0 + 32) * ATP + scol0] = vreg1;
        __syncthreads();
      }
      if (kt + 1 < nkt) {  // prefetch next K/V tile
        kreg0 = *(const u16x8*)(kp0 += 64 * 3072);
        kreg1 = *(const u16x8*)(kp1 += 64 * 3072);
        vreg0 = *(const u16x8*)(vp0 += 64);
        vreg1 = *(const u16x8*)(vp1 += 64);
      }

      // S^T = K . Q^T for both groups; kf fragments shared
      f32x4 s0[4] = {}, s1[4] = {};
#pragma unroll
      for (int mt = 0; mt < 4; ++mt) {
        short8 kf0 = *(const short8*)&Ks[(mt * 16 + l16) * ATP + quad * 8];
        short8 kf1 = *(const short8*)&Ks[(mt * 16 + l16) * ATP + 32 + quad * 8];
        if (g0mode < 2) {
          s0[mt] = mfma16(kf0, qf0a, s0[mt]);
          s0[mt] = mfma16(kf1, qf1a, s0[mt]);
        }
        s1[mt] = mfma16(kf0, qf0b, s1[mt]);
        s1[mt] = mfma16(kf1, qf1b, s1[mt]);
      }

      // softmax + P pack, group 0
      if (g0mode < 2) {
        const int qrow = q0 + wave * 16 + l16;
#pragma unroll
        for (int mt = 0; mt < 4; ++mt) {
          float pe[4];
#pragma unroll
          for (int r = 0; r < 4; ++r) {
            float pv = __builtin_amdgcn_exp2f(s0[mt][r]);
            if (g0mode == 1) {
              int kcol = kt * 64 + mt * 16 + quad * 4 + r;
              if (kcol > qrow) pv = 0.f;
            }
            pe[r] = pv;
          }
          u32 lo = __builtin_amdgcn_perm(__float_as_uint(pe[1]),
                                         __float_as_uint(pe[0]), 0x07060302u);
          u32 hi = __builtin_amdgcn_perm(__float_as_uint(pe[3]),
                                         __float_as_uint(pe[2]), 0x07060302u);
          uint2 pk = {lo, hi};
          *(uint2*)&Pw0[l16 * ATP + mt * 16 + quad * 4] = pk;
        }
      }
      // softmax + P pack, group 1
      {
        const int qrow = q0 + 64 + wave * 16 + l16;
#pragma unroll
        for (int mt = 0; mt < 4; ++mt) {
          float pe[4];
#pragma unroll
          for (int r = 0; r < 4; ++r) {
            float pv = __builtin_amdgcn_exp2f(s1[mt][r]);
            if (g1mask) {
              int kcol = kt * 64 + mt * 16 + quad * 4 + r;
              if (kcol > qrow) pv = 0.f;
            }
            pe[r] = pv;
          }
          u32 lo = __builtin_amdgcn_perm(__float_as_uint(pe[1]),
                                         __float_as_uint(pe[0]), 0x07060302u);
          u32 hi = __builtin_amdgcn_perm(__float_as_uint(pe[3]),
                                         __float_as_uint(pe[2]), 0x07060302u);
          uint2 pk = {lo, hi};
          *(uint2*)&Pw1[l16 * ATP + mt * 16 + quad * 4] = pk;
        }
      }

      // O += P.V ; l += P.1 — vf fragments shared between groups
#pragma unroll
      for (int ks = 0; ks < 2; ++ks) {
        short8 pf0, pf1;
        if (g0mode < 2) {
          pf0 = *(const short8*)&Pw0[l16 * ATP + ks * 32 + quad * 8];
          lacc0 = mfma16(pf0, ones_f, lacc0);
        }
        pf1 = *(const short8*)&Pw1[l16 * ATP + ks * 32 + quad * 8];
        lacc1 = mfma16(pf1, ones_f, lacc1);
#pragma unroll
        for (int dt = 0; dt < 4; ++dt) {
          short8 vf = *(const short8*)&Vs[(dt * 16 + l16) * ATP + ks * 32 + quad * 8];
          if (g0mode < 2) o0[dt] = mfma16(pf0, vf, o0[dt]);
          o1[dt] = mfma16(pf1, vf, o1[dt]);
        }
      }
    };

    for (int kt = 0; kt < nkt - 2; ++kt) tile(kt, 0, false);
    tile(nkt - 2, 1, false);  // group-0 diagonal; group 1 still full
    tile(nkt - 1, 2, true);   // group-1 diagonal; group 0 fully masked: skip

    // epilogue: lacc reg r = l for row quad*4+r — same rows as o[dt][r]
    size_t rb0 = (size_t)b * 2048 + q0 + wave * 16 + quad * 4;
#pragma unroll
    for (int r = 0; r < 4; ++r) {
      float inv = 1.f / lacc0[r];
#pragma unroll
      for (int dt = 0; dt < 4; ++dt)
        y[(rb0 + r) * 1024 + h * 64 + dt * 16 + l16] = f2bf(o0[dt][r] * inv);
    }
    size_t rb1 = rb0 + 64;
#pragma unroll
    for (int r = 0; r < 4; ++r) {
      float inv = 1.f / lacc1[r];
#pragma unroll
      for (int dt = 0; dt < 4; ++dt)
        y[(rb1 + r) * 1024 + h * 64 + dt * 16 + l16] = f2bf(o1[dt][r] * inv);
    }
  }
}

extern "C" void kernel_launch(void* const* d_in, const int* in_sizes, int n_in,
                              void* d_out, int out_size, void* d_ws, size_t ws_size,
                              hipStream_t stream) {
  const float* x = (const float*)d_in[0];
  const float* W_attn = (const float*)d_in[1];
  const float* b_attn = (const float*)d_in[2];
  const float* W_proj = (const float*)d_in[3];
  const float* b_proj = (const float*)d_in[4];
  float* out = (float*)d_out;
  char* ws = (char*)d_ws;
  u16* xb  = (u16*)(ws);               // x as bf16 [8192][1024]
  u16* wta = (u16*)(ws + 16777216);    // W_attn^T bf16 [3072][1024]
  u16* wtp = (u16*)(ws + 23068672);    // W_proj^T bf16 [1024][1024]
  u16* qkv = (u16*)(ws + 25165824);    // qkv bf16 [8192][3072] (Q pre-scaled)
  u16* vt  = (u16*)(ws + 75497472);    // V^T bf16 [b][h][64][2048]
  u16* y   = (u16*)(ws + 92274688);    // attn out bf16 [8192][1024]

  k_cvt<<<dim3(8192), 256, 0, stream>>>(x, xb);
  k_tw<<<dim3(48, 16), 256, 0, stream>>>(W_attn, wta, 1024, 3072);
  k_tw<<<dim3(16, 16), 256, 0, stream>>>(W_proj, wtp, 1024, 1024);
  gemm_bt<1, 1><<<dim3(64, 24), 256, 0, stream>>>(xb, wta, b_attn, qkv, nullptr, 8192, 3072, 1024);
  k_tv<<<dim3(32, 16, 4), 256, 0, stream>>>(qkv, vt);
  attn<<<dim3(8, 16, 4), 256, 0, stream>>>(qkv, vt, y);
  gemm_bt<0, 0><<<dim3(64, 8), 256, 0, stream>>>(y, wtp, b_proj, nullptr, out, 8192, 1024, 1024);
}

// Round 8
// 248.688 us; speedup vs baseline: 1.1224x; 1.0222x over previous
//
#include <hip/hip_runtime.h>

// B=4, T=2048, C=1024, H=16, D=64. fp32 in/out, bf16 internal compute.

typedef unsigned short u16;
typedef unsigned int u32;
typedef __attribute__((ext_vector_type(8))) unsigned short u16x8;
typedef __attribute__((ext_vector_type(4))) unsigned short u16x4;
typedef __attribute__((ext_vector_type(8))) short short8;
typedef __attribute__((ext_vector_type(4))) float f32x4;

__device__ inline u16 f2bf(float f) {
  unsigned u = __float_as_uint(f);
  u = (u + 0x7FFF + ((u >> 16) & 1)) >> 16;  // RNE
  return (u16)u;
}

__device__ inline f32x4 mfma16(short8 a, short8 b, f32x4 c) {
  return __builtin_amdgcn_mfma_f32_16x16x32_bf16(a, b, c, 0, 0, 0);
}

// ---------------- fp32 -> bf16 elementwise convert ----------------
__global__ __launch_bounds__(256) void k_cvt(const float* __restrict__ in,
                                             u16* __restrict__ out) {
  int i = (blockIdx.x * 256 + threadIdx.x) * 4;
  float4 v = *(const float4*)(in + i);
  u16x4 o = {f2bf(v.x), f2bf(v.y), f2bf(v.z), f2bf(v.w)};
  *(u16x4*)(out + i) = o;
}

// ------------- fp32 [R][Cc] -> bf16 transpose [Cc][R] -------------
__global__ __launch_bounds__(256) void k_tw(const float* __restrict__ in,
                                            u16* __restrict__ outT, int R, int Cc) {
  __shared__ u16 t[64][65];
  int c0 = blockIdx.x * 64, r0 = blockIdx.y * 64;
  int a = threadIdx.x & 63, w = threadIdx.x >> 6;
#pragma unroll
  for (int j = 0; j < 16; ++j) {
    int r = w + j * 4;
    t[r][a] = f2bf(in[(size_t)(r0 + r) * Cc + c0 + a]);
  }
  __syncthreads();
#pragma unroll
  for (int j = 0; j < 16; ++j) {
    int c = w + j * 4;
    outT[(size_t)(c0 + c) * R + r0 + a] = t[a][c];
  }
}

// ------- V slice of qkv -> Vt[b][h][d][t]  (bf16 transpose) -------
__global__ __launch_bounds__(256) void k_tv(const u16* __restrict__ qkv,
                                            u16* __restrict__ vt) {
  __shared__ u16 t[64][65];
  int t0 = blockIdx.x * 64, h = blockIdx.y, b = blockIdx.z;
  int a = threadIdx.x & 63, w = threadIdx.x >> 6;
#pragma unroll
  for (int j = 0; j < 16; ++j) {
    int tr = w + j * 4;
    t[tr][a] = qkv[(size_t)(b * 2048 + t0 + tr) * 3072 + 2048 + h * 64 + a];
  }
  __syncthreads();
#pragma unroll
  for (int j = 0; j < 16; ++j) {
    int d = w + j * 4;
    vt[((size_t)((b * 16 + h) * 64 + d)) * 2048 + t0 + a] = t[a][d];
  }
}

// ---- bf16 GEMM: A[M][K] x Bt[N][K] + bias -> bf16 or fp32 out ----
// 128x128 block tile, BK=64, REGISTER-STAGED prefetch: tile kt+1 is loaded
// global->VGPR during compute of tile kt; after the barrier only ds_write of
// already-arrived registers happens. The vmcnt wait at the seam is for loads
// issued a full compute-phase earlier -> no ~900cyc HBM drain at the barrier
// (r6/r7 showed that drain was the limiter of the global_load_lds version).
// Swizzled LDS layout (r7, measured 0 conflicts): chunk c of row r at slot
// c^(r&7); ds_write: each 8-lane group writes one full 128B row (all 32
// banks once); frag reads at slot (ks*4+quad)^(l16&7).
// QSCALE: multiply cols<1024 (Q slice of qkv) by 1/sqrt(64)*log2(e).
template <int OUTBF, int QSCALE>
__global__ __launch_bounds__(256) void gemm_bt(const u16* __restrict__ A,
                                               const u16* __restrict__ Bt,
                                               const float* __restrict__ bias,
                                               u16* __restrict__ outb,
                                               float* __restrict__ outf,
                                               int M, int N, int K) {
  __shared__ u16 As[128 * 64];
  __shared__ u16 Bs[128 * 64];
  const int m0 = blockIdx.x * 128, n0 = blockIdx.y * 128;
  const int tid = threadIdx.x, wave = tid >> 6, lane = tid & 63;
  const int quad = lane >> 4, l16 = lane & 15;
  const int wm = (wave & 1) * 64, wn = (wave >> 1) * 64;
  const int lrow = lane >> 3;      // 0..7 within the 8-row slab
  const int lch = lane & 7;        // global 16B chunk within the row
  const int slot = lch ^ lrow;     // swizzled LDS chunk slot
  const u16* sA[4];
  const u16* sB[4];
  int offA[4], offB[4];
#pragma unroll
  for (int j = 0; j < 4; ++j) {
    int r = wave * 32 + j * 8;     // slab base row (multiple of 8)
    sA[j] = A + (size_t)(m0 + r + lrow) * K + lch * 8;
    sB[j] = Bt + (size_t)(n0 + r + lrow) * K + lch * 8;
    offA[j] = (r + lrow) * 64 + slot * 8;
    offB[j] = offA[j];
  }
  // prologue: load tile 0 into regs
  u16x8 ra[4], rb[4];
#pragma unroll
  for (int j = 0; j < 4; ++j) {
    ra[j] = *(const u16x8*)(sA[j]);
    rb[j] = *(const u16x8*)(sB[j]);
  }
  f32x4 acc[4][4] = {};
  for (int kt = 0; kt < K; kt += 64) {
    __syncthreads();  // all waves done reading LDS tile kt-1
#pragma unroll
    for (int j = 0; j < 4; ++j) {
      *(u16x8*)&As[offA[j]] = ra[j];
      *(u16x8*)&Bs[offB[j]] = rb[j];
    }
    __syncthreads();
    if (kt + 64 < K) {  // prefetch tile kt+1 (latency hides under compute)
#pragma unroll
      for (int j = 0; j < 4; ++j) {
        ra[j] = *(const u16x8*)(sA[j] + kt + 64);
        rb[j] = *(const u16x8*)(sB[j] + kt + 64);
      }
    }
    const int sl = l16 & 7;
#pragma unroll
    for (int ks = 0; ks < 2; ++ks) {
      short8 af[4], bf[4];
#pragma unroll
      for (int mt = 0; mt < 4; ++mt)
        af[mt] = *(const short8*)(As + (wm + mt * 16 + l16) * 64 +
                                  ((ks * 4 + quad) ^ sl) * 8);
#pragma unroll
      for (int nt = 0; nt < 4; ++nt)
        bf[nt] = *(const short8*)(Bs + (wn + nt * 16 + l16) * 64 +
                                  ((ks * 4 + quad) ^ sl) * 8);
#pragma unroll
      for (int mt = 0; mt < 4; ++mt)
#pragma unroll
        for (int nt = 0; nt < 4; ++nt)
          acc[mt][nt] = mfma16(af[mt], bf[nt], acc[mt][nt]);
    }
  }
#pragma unroll
  for (int nt = 0; nt < 4; ++nt) {
    int col = n0 + wn + nt * 16 + l16;
    float bv = bias[col];
#pragma unroll
    for (int mt = 0; mt < 4; ++mt) {
      int rowb = m0 + wm + mt * 16 + quad * 4;
#pragma unroll
      for (int r = 0; r < 4; ++r) {
        float v = acc[mt][nt][r] + bv;
        if (QSCALE && col < 1024) v *= 0.18033688f;  // 0.125 * log2(e)
        if (OUTBF)
          outb[(size_t)(rowb + r) * N + col] = f2bf(v);
        else
          outf[(size_t)(rowb + r) * N + col] = v;
      }
    }
  }
}

// ----------------- fused causal flash attention -------------------
// grid (8, H, B): block p handles 128-row q-tiles {p, 15-p} → uniform 34
// k-tiles/block. Each wave owns TWO 16-row q-groups so every K/V LDS
// fragment read feeds 2 MFMAs. Fixed-reference softmax (Q pre-scaled by
// 0.125*log2e in gemm1; offset cancels in O/l — exact). l on the MFMA pipe
// (P·ones), C/D rows match o[]. Group-0 diagonal at nkt-2; skips nkt-1.
// LDS: P aliases the 128-row Q region (wave-private rows, in-order DS).
#define ATP 72  // LDS row stride (elems): 144B = 9x16B, conflict-light
__global__ __launch_bounds__(256) void attn(const u16* __restrict__ qkv,
                                            const u16* __restrict__ vt,
                                            u16* __restrict__ y) {
  __shared__ u16 shm[256 * ATP];  // 36.9 KB
  u16* Qs = shm;                  // 128 rows; aliased as P after frag reads
  u16* Ks = shm + 128 * ATP;      // 64 rows
  u16* Vs = shm + 192 * ATP;      // 64 rows, V^T: [d][t]
  const int p = blockIdx.x, h = blockIdx.y, b = blockIdx.z;
  const int tid = threadIdx.x, wave = tid >> 6, lane = tid & 63;
  const int quad = lane >> 4, l16 = lane & 15;
  const u16* Qg = qkv + (size_t)b * 2048 * 3072 + h * 64;
  const u16* Kg = Qg + 1024;
  const u16* Vtg = vt + (size_t)(b * 16 + h) * 64 * 2048;
  const int srow0 = tid >> 3, scol0 = (tid & 7) * 8;  // srow0 in [0,32)
  u16* Pw0 = Qs + (wave * 16) * ATP;        // group-0 P (wave-private rows)
  u16* Pw1 = Qs + (64 + wave * 16) * ATP;   // group-1 P
  short8 ones_f;
#pragma unroll
  for (int j = 0; j < 8; ++j) ones_f[j] = 0x3F80;  // bf16 1.0

  for (int half = 0; half < 2; ++half) {
    const int qb = half ? (15 - p) : p;
    const int q0 = qb * 128;
    const int nkt = 2 * qb + 2;
    const u16* kp0 = Kg + (size_t)srow0 * 3072 + scol0;
    const u16* kp1 = kp0 + 32 * 3072;
    const u16* vp0 = Vtg + (size_t)srow0 * 2048 + scol0;
    const u16* vp1 = vp0 + 32 * 2048;
    // ---- load Q 128x64 + K/V tile 0 into regs ----
    u16x8 qr0 = *(const u16x8*)(Qg + (size_t)(q0 + srow0) * 3072 + scol0);
    u16x8 qr1 = *(const u16x8*)(Qg + (size_t)(q0 + srow0 + 32) * 3072 + scol0);
    u16x8 qr2 = *(const u16x8*)(Qg + (size_t)(q0 + srow0 + 64) * 3072 + scol0);
    u16x8 qr3 = *(const u16x8*)(Qg + (size_t)(q0 + srow0 + 96) * 3072 + scol0);
    u16x8 kreg0 = *(const u16x8*)kp0, kreg1 = *(const u16x8*)kp1;
    u16x8 vreg0 = *(const u16x8*)vp0, vreg1 = *(const u16x8*)vp1;
    __syncthreads();  // previous q-tile's LDS reads (incl. P) complete
    *(u16x8*)&Qs[(size_t)srow0 * ATP + scol0] = qr0;
    *(u16x8*)&Qs[(size_t)(srow0 + 32) * ATP + scol0] = qr1;
    *(u16x8*)&Qs[(size_t)(srow0 + 64) * ATP + scol0] = qr2;
    *(u16x8*)&Qs[(size_t)(srow0 + 96) * ATP + scol0] = qr3;
    *(u16x8*)&Ks[(size_t)srow0 * ATP + scol0] = kreg0;
    *(u16x8*)&Ks[(size_t)(srow0 + 32) * ATP + scol0] = kreg1;
    *(u16x8*)&Vs[(size_t)srow0 * ATP + scol0] = vreg0;
    *(u16x8*)&Vs[(size_t)(srow0 + 32) * ATP + scol0] = vreg1;
    __syncthreads();
    // Q fragments for both groups (wave reads only its own P-alias rows)
    short8 qf0a = *(const short8*)&Qs[(wave * 16 + l16) * ATP + quad * 8];
    short8 qf1a = *(const short8*)&Qs[(wave * 16 + l16) * ATP + 32 + quad * 8];
    short8 qf0b = *(const short8*)&Qs[(64 + wave * 16 + l16) * ATP + quad * 8];
    short8 qf1b = *(const short8*)&Qs[(64 + wave * 16 + l16) * ATP + 32 + quad * 8];

    f32x4 lacc0 = {}, lacc1 = {};
    f32x4 o0[4] = {}, o1[4] = {};

    // g0mode: 0=full, 1=diag-mask, 2=skip. g1mask: diag-mask group 1.
    auto tile = [&](int kt, int g0mode, bool g1mask) {
      if (kt > 0) {
        __syncthreads();  // all waves done reading tile kt-1
        *(u16x8*)&Ks[(size_t)srow0 * ATP + scol0] = kreg0;
        *(u16x8*)&Ks[(size_t)(srow0 + 32) * ATP + scol0] = kreg1;
        *(u16x8*)&Vs[(size_t)srow0 * ATP + scol0] = vreg0;
        *(u16x8*)&Vs[(size_t)(srow0 + 32) * ATP + scol0] = vreg1;
        __syncthreads();
      }
      if (kt + 1 < nkt) {  // prefetch next K/V tile
        kreg0 = *(const u16x8*)(kp0 += 64 * 3072);
        kreg1 = *(const u16x8*)(kp1 += 64 * 3072);
        vreg0 = *(const u16x8*)(vp0 += 64);
        vreg1 = *(const u16x8*)(vp1 += 64);
      }

      // S^T = K . Q^T for both groups; kf fragments shared
      f32x4 s0[4] = {}, s1[4] = {};
#pragma unroll
      for (int mt = 0; mt < 4; ++mt) {
        short8 kf0 = *(const short8*)&Ks[(mt * 16 + l16) * ATP + quad * 8];
        short8 kf1 = *(const short8*)&Ks[(mt * 16 + l16) * ATP + 32 + quad * 8];
        if (g0mode < 2) {
          s0[mt] = mfma16(kf0, qf0a, s0[mt]);
          s0[mt] = mfma16(kf1, qf1a, s0[mt]);
        }
        s1[mt] = mfma16(kf0, qf0b, s1[mt]);
        s1[mt] = mfma16(kf1, qf1b, s1[mt]);
      }

      // softmax + P pack, group 0
      if (g0mode < 2) {
        const int qrow = q0 + wave * 16 + l16;
#pragma unroll
        for (int mt = 0; mt < 4; ++mt) {
          float pe[4];
#pragma unroll
          for (int r = 0; r < 4; ++r) {
            float pv = __builtin_amdgcn_exp2f(s0[mt][r]);
            if (g0mode == 1) {
              int kcol = kt * 64 + mt * 16 + quad * 4 + r;
              if (kcol > qrow) pv = 0.f;
            }
            pe[r] = pv;
          }
          u32 lo = __builtin_amdgcn_perm(__float_as_uint(pe[1]),
                                         __float_as_uint(pe[0]), 0x07060302u);
          u32 hi = __builtin_amdgcn_perm(__float_as_uint(pe[3]),
                                         __float_as_uint(pe[2]), 0x07060302u);
          uint2 pk = {lo, hi};
          *(uint2*)&Pw0[l16 * ATP + mt * 16 + quad * 4] = pk;
        }
      }
      // softmax + P pack, group 1
      {
        const int qrow = q0 + 64 + wave * 16 + l16;
#pragma unroll
        for (int mt = 0; mt < 4; ++mt) {
          float pe[4];
#pragma unroll
          for (int r = 0; r < 4; ++r) {
            float pv = __builtin_amdgcn_exp2f(s1[mt][r]);
            if (g1mask) {
              int kcol = kt * 64 + mt * 16 + quad * 4 + r;
              if (kcol > qrow) pv = 0.f;
            }
            pe[r] = pv;
          }
          u32 lo = __builtin_amdgcn_perm(__float_as_uint(pe[1]),
                                         __float_as_uint(pe[0]), 0x07060302u);
          u32 hi = __builtin_amdgcn_perm(__float_as_uint(pe[3]),
                                         __float_as_uint(pe[2]), 0x07060302u);
          uint2 pk = {lo, hi};
          *(uint2*)&Pw1[l16 * ATP + mt * 16 + quad * 4] = pk;
        }
      }

      // O += P.V ; l += P.1 — vf fragments shared between groups
#pragma unroll
      for (int ks = 0; ks < 2; ++ks) {
        short8 pf0, pf1;
        if (g0mode < 2) {
          pf0 = *(const short8*)&Pw0[l16 * ATP + ks * 32 + quad * 8];
          lacc0 = mfma16(pf0, ones_f, lacc0);
        }
        pf1 = *(const short8*)&Pw1[l16 * ATP + ks * 32 + quad * 8];
        lacc1 = mfma16(pf1, ones_f, lacc1);
#pragma unroll
        for (int dt = 0; dt < 4; ++dt) {
          short8 vf = *(const short8*)&Vs[(dt * 16 + l16) * ATP + ks * 32 + quad * 8];
          if (g0mode < 2) o0[dt] = mfma16(pf0, vf, o0[dt]);
          o1[dt] = mfma16(pf1, vf, o1[dt]);
        }
      }
    };

    for (int kt = 0; kt < nkt - 2; ++kt) tile(kt, 0, false);
    tile(nkt - 2, 1, false);  // group-0 diagonal; group 1 still full
    tile(nkt - 1, 2, true);   // group-1 diagonal; group 0 fully masked: skip

    // epilogue: lacc reg r = l for row quad*4+r — same rows as o[dt][r]
    size_t rb0 = (size_t)b * 2048 + q0 + wave * 16 + quad * 4;
#pragma unroll
    for (int r = 0; r < 4; ++r) {
      float inv = 1.f / lacc0[r];
#pragma unroll
      for (int dt = 0; dt < 4; ++dt)
        y[(rb0 + r) * 1024 + h * 64 + dt * 16 + l16] = f2bf(o0[dt][r] * inv);
    }
    size_t rb1 = rb0 + 64;
#pragma unroll
    for (int r = 0; r < 4; ++r) {
      float inv = 1.f / lacc1[r];
#pragma unroll
      for (int dt = 0; dt < 4; ++dt)
        y[(rb1 + r) * 1024 + h * 64 + dt * 16 + l16] = f2bf(o1[dt][r] * inv);
    }
  }
}

extern "C" void kernel_launch(void* const* d_in, const int* in_sizes, int n_in,
                              void* d_out, int out_size, void* d_ws, size_t ws_size,
                              hipStream_t stream) {
  const float* x = (const float*)d_in[0];
  const float* W_attn = (const float*)d_in[1];
  const float* b_attn = (const float*)d_in[2];
  const float* W_proj = (const float*)d_in[3];
  const float* b_proj = (const float*)d_in[4];
  float* out = (float*)d_out;
  char* ws = (char*)d_ws;
  u16* xb  = (u16*)(ws);               // x as bf16 [8192][1024]
  u16* wta = (u16*)(ws + 16777216);    // W_attn^T bf16 [3072][1024]
  u16* wtp = (u16*)(ws + 23068672);    // W_proj^T bf16 [1024][1024]
  u16* qkv = (u16*)(ws + 25165824);    // qkv bf16 [8192][3072] (Q pre-scaled)
  u16* vt  = (u16*)(ws + 75497472);    // V^T bf16 [b][h][64][2048]
  u16* y   = (u16*)(ws + 92274688);    // attn out bf16 [8192][1024]

  k_cvt<<<dim3(8192), 256, 0, stream>>>(x, xb);
  k_tw<<<dim3(48, 16), 256, 0, stream>>>(W_attn, wta, 1024, 3072);
  k_tw<<<dim3(16, 16), 256, 0, stream>>>(W_proj, wtp, 1024, 1024);
  gemm_bt<1, 1><<<dim3(64, 24), 256, 0, stream>>>(xb, wta, b_attn, qkv, nullptr, 8192, 3072, 1024);
  k_tv<<<dim3(32, 16, 4), 256, 0, stream>>>(qkv, vt);
  attn<<<dim3(8, 16, 4), 256, 0, stream>>>(qkv, vt, y);
  gemm_bt<0, 0><<<dim3(64, 8), 256, 0, stream>>>(y, wtp, b_proj, nullptr, out, 8192, 1024, 1024);
}